// Round 1
// baseline (96.152 us; speedup 1.0000x reference)
//
#include <hip/hip_runtime.h>
#include <cstdint>

#define BB 256
#define NN 128
#define DD 512
#define HH 512

typedef __attribute__((ext_vector_type(8))) short bf16x8;
typedef __attribute__((ext_vector_type(4))) float f32x4;
typedef unsigned short u16;

static __device__ __forceinline__ u16 f2bf(float f) {
    union { float f; uint32_t u; } v; v.f = f;
    uint32_t u = v.u;
    return (u16)((u + 0x7FFFu + ((u >> 16) & 1u)) >> 16);
}
static __device__ __forceinline__ float bf2f(u16 h) {
    union { uint32_t u; float f; } v; v.u = ((uint32_t)h) << 16;
    return v.f;
}

// ---------------- W fp32 -> bf16 (once) ----------------
__global__ __launch_bounds__(256) void wconv_kernel(const float* __restrict__ W, u16* __restrict__ Wb) {
    int idx = (blockIdx.x * 256 + threadIdx.x) * 4;   // grid 256 * 256 thr * 4 = 262144 = H*D
    float4 v = *(const float4*)(W + idx);
    ushort4 o;
    o.x = f2bf(v.x); o.y = f2bf(v.y); o.z = f2bf(v.z); o.w = f2bf(v.w);
    *(ushort4*)(Wb + idx) = o;
}

// ---------------- per-batch aggregation: X_agg = X + A_norm @ X ----------------
// grid = 512 (2 blocks per batch, each does 2 d-tiles of 128), 256 threads (4 waves)
__global__ __launch_bounds__(256, 2) void agg_kernel(const float* __restrict__ X, const float* __restrict__ A,
                                                     u16* __restrict__ Xagg) {
    __shared__ u16 Anorm[128][128];   // A_norm[i][m], block-swizzled on m
    __shared__ u16 Xt[128][128];      // X^T tile: [d][m], block-swizzled on m

    const int t = threadIdx.x;
    const int batch = blockIdx.x >> 1;
    const int half = blockIdx.x & 1;
    const int lane = t & 63;
    const int w = t >> 6;        // wave 0..3 -> i-rows [32w, 32w+32)
    const int g = lane >> 4;
    const int l16 = lane & 15;

    // Phase 1: load A rows, shfl row-sum (32 lanes cover one full 128-row), normalize, store bf16 swizzled.
    const float* Ab = A + (size_t)batch * (NN * NN);
    #pragma unroll
    for (int it = 0; it < 16; ++it) {
        int q = t + it * 256;
        int c = q & 31;          // float4 column (c == lane%32)
        int row = q >> 5;
        float4 v = *(const float4*)(Ab + row * NN + c * 4);
        float s = v.x + v.y + v.z + v.w;
        s += __shfl_xor(s, 1);
        s += __shfl_xor(s, 2);
        s += __shfl_xor(s, 4);
        s += __shfl_xor(s, 8);
        s += __shfl_xor(s, 16);
        float inv = 1.0f / (s + 1e-6f);
        ushort4 o;
        o.x = f2bf(v.x * inv); o.y = f2bf(v.y * inv); o.z = f2bf(v.z * inv); o.w = f2bf(v.w * inv);
        // element m=4c+r lives at col ((m>>3)^(row&15))*8 + (m&7); 4 consecutive -> one 8B store
        int col = (((c >> 1) ^ (row & 15)) << 3) + ((c & 1) << 2);
        *(ushort4*)&Anorm[row][col] = o;
    }
    __syncthreads();

    for (int dti = 0; dti < 2; ++dti) {
        const int dt = half * 2 + dti;
        // Phase 2a: stage X tile transposed: Xt[d][m] = X[m][dt*128+d] (bf16, swizzled)
        const float* Xb = X + (size_t)batch * (NN * DD) + dt * 128;
        #pragma unroll
        for (int it = 0; it < 16; ++it) {
            int q = t + it * 256;
            int c = q & 31;
            int m = q >> 5;
            float4 v = *(const float4*)(Xb + (size_t)m * DD + c * 4);
            float fv[4] = {v.x, v.y, v.z, v.w};
            #pragma unroll
            for (int r = 0; r < 4; ++r) {
                int d = c * 4 + r;
                Xt[d][(((m >> 3) ^ (d & 15)) << 3) + (m & 7)] = f2bf(fv[r]);
            }
        }
        __syncthreads();

        // Phase 2b: MFMA. wave tile = 32 i-rows x 128 d-cols = 2x8 fragments
        f32x4 acc[2][8];
        #pragma unroll
        for (int ti = 0; ti < 2; ++ti)
            #pragma unroll
            for (int tj = 0; tj < 8; ++tj)
                acc[ti][tj] = (f32x4){0.f, 0.f, 0.f, 0.f};

        #pragma unroll
        for (int kk = 0; kk < 4; ++kk) {      // K = 128, 32 per step
            bf16x8 af[2];
            #pragma unroll
            for (int ti = 0; ti < 2; ++ti) {
                int i = w * 32 + ti * 16 + l16;
                af[ti] = *(const bf16x8*)&Anorm[i][(((kk * 4 + g) ^ (i & 15)) << 3)];
            }
            #pragma unroll
            for (int tj = 0; tj < 8; ++tj) {
                int d = tj * 16 + l16;
                bf16x8 bfr = *(const bf16x8*)&Xt[d][(((kk * 4 + g) ^ (d & 15)) << 3)];
                #pragma unroll
                for (int ti = 0; ti < 2; ++ti)
                    acc[ti][tj] = __builtin_amdgcn_mfma_f32_16x16x32_bf16(af[ti], bfr, acc[ti][tj], 0, 0, 0);
            }
        }

        // Phase 2c: X_agg = acc + X  (X read back from Xt), write bf16 row-major [i][d]
        u16* Og = Xagg + (size_t)batch * (NN * DD) + dt * 128;
        #pragma unroll
        for (int ti = 0; ti < 2; ++ti) {
            #pragma unroll
            for (int tj = 0; tj < 8; ++tj) {
                #pragma unroll
                for (int r = 0; r < 4; ++r) {
                    int i = w * 32 + ti * 16 + g * 4 + r;
                    int d = tj * 16 + l16;
                    float xv = bf2f(Xt[d][(((i >> 3) ^ (d & 15)) << 3) + (i & 7)]);
                    Og[(size_t)i * DD + d] = f2bf(acc[ti][tj][r] + xv);
                }
            }
        }
        __syncthreads();   // before next tile overwrites Xt
    }
}

// ---------------- big GEMM + bias + LayerNorm + sigmoid ----------------
// grid = 32768/64 = 512 blocks, 512 threads (8 waves, wave w -> cols [64w,64w+64))
__global__ __launch_bounds__(512, 4) void gemm_ln_kernel(const u16* __restrict__ Xagg, const u16* __restrict__ Wb,
                                                         const float* __restrict__ bias, const float* __restrict__ lnw,
                                                         const float* __restrict__ lnb, float* __restrict__ out) {
    __shared__ __align__(16) char smem[66560];             // Ws+As overlaid by Xup after K-loop
    u16 (*Ws)[40] = (u16(*)[40])smem;                      // [512][40] = 40960 B
    u16 (*As)[40] = (u16(*)[40])(smem + 40960);            // [64][40]  = 5120 B
    u16 (*Xup)[520] = (u16(*)[520])smem;                   // [64][520] = 66560 B
    __shared__ float bias_s[512], lnw_s[512], lnb_s[512];

    const int t = threadIdx.x;
    const int lane = t & 63;
    const int w = t >> 6;
    const int g = lane >> 4;
    const int l16 = lane & 15;
    const size_t rb = (size_t)blockIdx.x * 64;

    bias_s[t] = bias[t];
    lnw_s[t] = lnw[t];
    lnb_s[t] = lnb[t];

    f32x4 acc[4][4];
    #pragma unroll
    for (int ti = 0; ti < 4; ++ti)
        #pragma unroll
        for (int tj = 0; tj < 4; ++tj)
            acc[ti][tj] = (f32x4){0.f, 0.f, 0.f, 0.f};

    for (int ks = 0; ks < 16; ++ks) {
        const int k0 = ks * 32;
        __syncthreads();   // previous-step fragment reads done before restaging
        {   // stage W slab [512][32]: 4 rows-chunks per thread
            int row = t >> 2;
            int ch = t & 3;
            #pragma unroll
            for (int it = 0; it < 4; ++it) {
                int rr = row + it * 128;
                uint4 v = *(const uint4*)(Wb + (size_t)rr * DD + k0 + ch * 8);
                *(uint4*)&Ws[rr][ch * 8] = v;
            }
        }
        if (t < 256) {   // stage A slab [64][32]
            int row = t >> 2;
            int ch = t & 3;
            uint4 v = *(const uint4*)(Xagg + (rb + row) * DD + k0 + ch * 8);
            *(uint4*)&As[row][ch * 8] = v;
        }
        __syncthreads();

        bf16x8 afr[4], bfr[4];
        #pragma unroll
        for (int ti = 0; ti < 4; ++ti)
            afr[ti] = *(const bf16x8*)&As[ti * 16 + l16][g * 8];
        #pragma unroll
        for (int tj = 0; tj < 4; ++tj)
            bfr[tj] = *(const bf16x8*)&Ws[w * 64 + tj * 16 + l16][g * 8];
        #pragma unroll
        for (int ti = 0; ti < 4; ++ti)
            #pragma unroll
            for (int tj = 0; tj < 4; ++tj)
                acc[ti][tj] = __builtin_amdgcn_mfma_f32_16x16x32_bf16(afr[ti], bfr[tj], acc[ti][tj], 0, 0, 0);
    }
    __syncthreads();   // K-loop reads done; smem becomes Xup

    // stage X_up (+bias) as bf16
    #pragma unroll
    for (int ti = 0; ti < 4; ++ti)
        #pragma unroll
        for (int tj = 0; tj < 4; ++tj)
            #pragma unroll
            for (int r = 0; r < 4; ++r) {
                int row = ti * 16 + g * 4 + r;
                int col = w * 64 + tj * 16 + l16;
                Xup[row][col] = f2bf(acc[ti][tj][r] + bias_s[col]);
            }
    __syncthreads();

    // LayerNorm + sigmoid: 8 threads per row, 64 values each
    {
        const int row = t >> 3;
        const int seg = t & 7;
        float s = 0.f, ss = 0.f;
        #pragma unroll
        for (int j = 0; j < 8; ++j) {
            uint4 v = *(const uint4*)&Xup[row][seg * 64 + j * 8];
            const u16* pv = (const u16*)&v;
            #pragma unroll
            for (int e = 0; e < 8; ++e) {
                float f = bf2f(pv[e]);
                s += f; ss += f * f;
            }
        }
        s += __shfl_xor(s, 1); ss += __shfl_xor(ss, 1);
        s += __shfl_xor(s, 2); ss += __shfl_xor(ss, 2);
        s += __shfl_xor(s, 4); ss += __shfl_xor(ss, 4);
        const float mean = s * (1.0f / 512.0f);
        const float var = ss * (1.0f / 512.0f) - mean * mean;
        const float rstd = rsqrtf(var + 1e-5f);

        float* op = out + (rb + row) * HH + seg * 64;
        #pragma unroll
        for (int j = 0; j < 8; ++j) {
            uint4 v = *(const uint4*)&Xup[row][seg * 64 + j * 8];
            const u16* pv = (const u16*)&v;
            float4 o[2];
            #pragma unroll
            for (int e = 0; e < 8; ++e) {
                int h = seg * 64 + j * 8 + e;
                float xn = (bf2f(pv[e]) - mean) * rstd * lnw_s[h] + lnb_s[h];
                ((float*)o)[e] = 1.0f / (1.0f + __expf(-xn));
            }
            *(float4*)(op + j * 8) = o[0];
            *(float4*)(op + j * 8 + 4) = o[1];
        }
    }
}

extern "C" void kernel_launch(void* const* d_in, const int* in_sizes, int n_in,
                              void* d_out, int out_size, void* d_ws, size_t ws_size,
                              hipStream_t stream) {
    const float* X = (const float*)d_in[0];
    const float* A = (const float*)d_in[1];
    const float* W = (const float*)d_in[2];
    const float* bias = (const float*)d_in[3];
    const float* lnw = (const float*)d_in[4];
    const float* lnb = (const float*)d_in[5];
    float* out = (float*)d_out;

    u16* Xagg = (u16*)d_ws;                                  // B*N*D bf16 = 32 MB
    u16* Wb = (u16*)d_ws + (size_t)BB * NN * DD;             // H*D bf16 = 512 KB

    hipLaunchKernelGGL(wconv_kernel, dim3(256), dim3(256), 0, stream, W, Wb);
    hipLaunchKernelGGL(agg_kernel, dim3(512), dim3(256), 0, stream, X, A, Xagg);
    hipLaunchKernelGGL(gemm_ln_kernel, dim3(512), dim3(512), 0, stream, Xagg, Wb, bias, lnw, lnb, out);
}

// Round 2
// 94.731 us; speedup vs baseline: 1.0150x; 1.0150x over previous
//
#include <hip/hip_runtime.h>
#include <cstdint>

#define BB 256
#define NN 128
#define DD 512
#define HH 512

typedef __attribute__((ext_vector_type(8))) short bf16x8;
typedef __attribute__((ext_vector_type(4))) float f32x4;
typedef __attribute__((ext_vector_type(16))) float f32x16;
typedef unsigned short u16;

static __device__ __forceinline__ u16 f2bf(float f) {
    union { float f; uint32_t u; } v; v.f = f;
    uint32_t u = v.u;
    return (u16)((u + 0x7FFFu + ((u >> 16) & 1u)) >> 16);
}
static __device__ __forceinline__ float bf2f(u16 h) {
    union { uint32_t u; float f; } v; v.u = ((uint32_t)h) << 16;
    return v.f;
}

static __device__ __forceinline__ void gload16(const u16* g, u16* l) {
    __builtin_amdgcn_global_load_lds((const __attribute__((address_space(1))) void*)g,
                                     (__attribute__((address_space(3))) void*)l, 16, 0, 0);
}

// ---------------- W fp32 -> bf16 (once) ----------------
__global__ __launch_bounds__(256) void wconv_kernel(const float* __restrict__ W, u16* __restrict__ Wb) {
    int idx = (blockIdx.x * 256 + threadIdx.x) * 4;
    float4 v = *(const float4*)(W + idx);
    ushort4 o;
    o.x = f2bf(v.x); o.y = f2bf(v.y); o.z = f2bf(v.z); o.w = f2bf(v.w);
    *(ushort4*)(Wb + idx) = o;
}

// ---------------- per-batch aggregation: X_agg = X + A_norm @ X ----------------
__global__ __launch_bounds__(256, 2) void agg_kernel(const float* __restrict__ X, const float* __restrict__ A,
                                                     u16* __restrict__ Xagg) {
    __shared__ u16 Anorm[128][128];
    __shared__ u16 Xt[128][128];

    const int t = threadIdx.x;
    const int batch = blockIdx.x >> 1;
    const int half = blockIdx.x & 1;
    const int lane = t & 63;
    const int w = t >> 6;
    const int g = lane >> 4;
    const int l16 = lane & 15;

    const float* Ab = A + (size_t)batch * (NN * NN);
    #pragma unroll
    for (int it = 0; it < 16; ++it) {
        int q = t + it * 256;
        int c = q & 31;
        int row = q >> 5;
        float4 v = *(const float4*)(Ab + row * NN + c * 4);
        float s = v.x + v.y + v.z + v.w;
        s += __shfl_xor(s, 1);
        s += __shfl_xor(s, 2);
        s += __shfl_xor(s, 4);
        s += __shfl_xor(s, 8);
        s += __shfl_xor(s, 16);
        float inv = 1.0f / (s + 1e-6f);
        ushort4 o;
        o.x = f2bf(v.x * inv); o.y = f2bf(v.y * inv); o.z = f2bf(v.z * inv); o.w = f2bf(v.w * inv);
        int col = (((c >> 1) ^ (row & 15)) << 3) + ((c & 1) << 2);
        *(ushort4*)&Anorm[row][col] = o;
    }
    __syncthreads();

    for (int dti = 0; dti < 2; ++dti) {
        const int dt = half * 2 + dti;
        const float* Xb = X + (size_t)batch * (NN * DD) + dt * 128;
        #pragma unroll
        for (int it = 0; it < 16; ++it) {
            int q = t + it * 256;
            int c = q & 31;
            int m = q >> 5;
            float4 v = *(const float4*)(Xb + (size_t)m * DD + c * 4);
            float fv[4] = {v.x, v.y, v.z, v.w};
            #pragma unroll
            for (int r = 0; r < 4; ++r) {
                int d = c * 4 + r;
                Xt[d][(((m >> 3) ^ (d & 15)) << 3) + (m & 7)] = f2bf(fv[r]);
            }
        }
        __syncthreads();

        f32x4 acc[2][8];
        #pragma unroll
        for (int ti = 0; ti < 2; ++ti)
            #pragma unroll
            for (int tj = 0; tj < 8; ++tj)
                acc[ti][tj] = (f32x4){0.f, 0.f, 0.f, 0.f};

        #pragma unroll
        for (int kk = 0; kk < 4; ++kk) {
            bf16x8 af[2];
            #pragma unroll
            for (int ti = 0; ti < 2; ++ti) {
                int i = w * 32 + ti * 16 + l16;
                af[ti] = *(const bf16x8*)&Anorm[i][(((kk * 4 + g) ^ (i & 15)) << 3)];
            }
            #pragma unroll
            for (int tj = 0; tj < 8; ++tj) {
                int d = tj * 16 + l16;
                bf16x8 bfr = *(const bf16x8*)&Xt[d][(((kk * 4 + g) ^ (d & 15)) << 3)];
                #pragma unroll
                for (int ti = 0; ti < 2; ++ti)
                    acc[ti][tj] = __builtin_amdgcn_mfma_f32_16x16x32_bf16(af[ti], bfr, acc[ti][tj], 0, 0, 0);
            }
        }

        u16* Og = Xagg + (size_t)batch * (NN * DD) + dt * 128;
        #pragma unroll
        for (int ti = 0; ti < 2; ++ti) {
            #pragma unroll
            for (int tj = 0; tj < 8; ++tj) {
                #pragma unroll
                for (int r = 0; r < 4; ++r) {
                    int i = w * 32 + ti * 16 + g * 4 + r;
                    int d = tj * 16 + l16;
                    float xv = bf2f(Xt[d][(((i >> 3) ^ (d & 15)) << 3) + (i & 7)]);
                    Og[(size_t)i * DD + d] = f2bf(acc[ti][tj][r] + xv);
                }
            }
        }
        __syncthreads();
    }
}

// ---------------- big GEMM + bias + LayerNorm + sigmoid ----------------
// grid 256 blocks (1/CU), 512 threads = 8 waves (2M x 4N), M-tile 128, N 512, BK 32 dbuf
__global__ __launch_bounds__(512, 2) void gemm_ln_kernel(const u16* __restrict__ Xagg, const u16* __restrict__ Wb,
                                                         const float* __restrict__ bias, const float* __restrict__ lnw,
                                                         const float* __restrict__ lnb, float* __restrict__ out) {
    // [0,65536): W slabs 2 x [512][32] swizzled; [65536,81920): A slabs 2 x [128][32]
    __shared__ __align__(16) char smem[81920];

    const int t = threadIdx.x;
    const int lane = t & 63;
    const int w = t >> 6;
    const int wm = w >> 2;         // 0..1
    const int wn = w & 3;          // 0..3
    const int l31 = lane & 31;
    const int lh = lane >> 5;
    const size_t rb = (size_t)blockIdx.x * 128;

    f32x16 acc[2][4];
    #pragma unroll
    for (int mi = 0; mi < 2; ++mi)
        #pragma unroll
        for (int nf = 0; nf < 4; ++nf)
            #pragma unroll
            for (int r = 0; r < 16; ++r)
                acc[mi][nf][r] = 0.f;

#define STAGE(KS, BUF)                                                                 \
    {                                                                                  \
        const int k0_ = (KS) * 32;                                                     \
        u16* al_ = (u16*)(smem + 65536 + (BUF) * 8192);                                \
        u16* wl_ = (u16*)(smem + (BUF) * 32768);                                       \
        {                                                                              \
            int row_ = t >> 2, cp_ = t & 3;                                            \
            int ch_ = cp_ ^ ((row_ >> 1) & 3);                                         \
            gload16(Xagg + (rb + row_) * DD + k0_ + ch_ * 8, al_ + t * 8);             \
        }                                                                              \
        _Pragma("unroll")                                                              \
        for (int it_ = 0; it_ < 4; ++it_) {                                            \
            int q_ = it_ * 512 + t;                                                    \
            int row_ = q_ >> 2, cp_ = q_ & 3;                                          \
            int ch_ = cp_ ^ ((row_ >> 1) & 3);                                         \
            gload16(Wb + (size_t)row_ * DD + k0_ + ch_ * 8, wl_ + q_ * 8);             \
        }                                                                              \
    }

    STAGE(0, 0);
    for (int ks = 0; ks < 16; ++ks) {
        const int buf = ks & 1;
        if (ks < 15) {
            STAGE(ks + 1, buf ^ 1);
            asm volatile("s_waitcnt vmcnt(5)" ::: "memory");   // own cur-buffer loads done; next 5 in flight
        } else {
            asm volatile("s_waitcnt vmcnt(0)" ::: "memory");
        }
        __builtin_amdgcn_s_barrier();
        asm volatile("" ::: "memory");

        const u16* wl = (const u16*)(smem + buf * 32768);
        const u16* al = (const u16*)(smem + 65536 + buf * 8192);
        #pragma unroll
        for (int s = 0; s < 2; ++s) {
            const int kc = s * 2 + lh;    // 16B k-chunk index within BK=32
            bf16x8 af[2];
            #pragma unroll
            for (int mi = 0; mi < 2; ++mi) {
                int row = wm * 64 + mi * 32 + l31;
                af[mi] = *(const bf16x8*)(al + (row * 4 + (kc ^ ((row >> 1) & 3))) * 8);
            }
            bf16x8 bw[4];
            #pragma unroll
            for (int nf = 0; nf < 4; ++nf) {
                int h = wn * 128 + nf * 32 + l31;
                bw[nf] = *(const bf16x8*)(wl + (h * 4 + (kc ^ ((h >> 1) & 3))) * 8);
            }
            #pragma unroll
            for (int mi = 0; mi < 2; ++mi)
                #pragma unroll
                for (int nf = 0; nf < 4; ++nf)
                    acc[mi][nf] = __builtin_amdgcn_mfma_f32_32x32x16_bf16(af[mi], bw[nf], acc[mi][nf], 0, 0, 0);
        }
        asm volatile("" ::: "memory");
        __builtin_amdgcn_s_barrier();
    }
    __syncthreads();   // slabs dead; smem becomes stats scratch

    // bias into acc; per-lane column params
    float bias_v[4], lnw_v[4], lnb_v[4];
    #pragma unroll
    for (int nf = 0; nf < 4; ++nf) {
        int col = wn * 128 + nf * 32 + l31;
        bias_v[nf] = bias[col];
        lnw_v[nf] = lnw[col];
        lnb_v[nf] = lnb[col];
    }
    #pragma unroll
    for (int mi = 0; mi < 2; ++mi)
        #pragma unroll
        for (int nf = 0; nf < 4; ++nf)
            #pragma unroll
            for (int r = 0; r < 16; ++r)
                acc[mi][nf][r] += bias_v[nf];

    // per-row partial stats across this wave's 128 cols (reduce over 32-lane col group)
    float rs[2][16], rss[2][16];
    #pragma unroll
    for (int mi = 0; mi < 2; ++mi)
        #pragma unroll
        for (int r = 0; r < 16; ++r) {
            float a0 = acc[mi][0][r], a1 = acc[mi][1][r], a2 = acc[mi][2][r], a3 = acc[mi][3][r];
            rs[mi][r] = a0 + a1 + a2 + a3;
            rss[mi][r] = a0 * a0 + a1 * a1 + a2 * a2 + a3 * a3;
        }
    #pragma unroll
    for (int msk = 1; msk <= 16; msk <<= 1) {
        #pragma unroll
        for (int mi = 0; mi < 2; ++mi)
            #pragma unroll
            for (int r = 0; r < 16; ++r) {
                rs[mi][r] += __shfl_xor(rs[mi][r], msk);
                rss[mi][r] += __shfl_xor(rss[mi][r], msk);
            }
    }

    float* Pss = (float*)smem;              // [4][128][2]
    float* musig = (float*)(smem + 4096);   // [128][2]
    if (l31 == 0) {
        #pragma unroll
        for (int mi = 0; mi < 2; ++mi)
            #pragma unroll
            for (int r = 0; r < 16; ++r) {
                int row = wm * 64 + mi * 32 + (r & 3) + 8 * (r >> 2) + 4 * lh;
                float2 v; v.x = rs[mi][r]; v.y = rss[mi][r];
                *(float2*)(Pss + (wn * 128 + row) * 2) = v;
            }
    }
    __syncthreads();
    if (t < 128) {
        float s = 0.f, ss = 0.f;
        #pragma unroll
        for (int q = 0; q < 4; ++q) {
            float2 v = *(const float2*)(Pss + (q * 128 + t) * 2);
            s += v.x; ss += v.y;
        }
        float mean = s * (1.0f / 512.0f);
        float var = ss * (1.0f / 512.0f) - mean * mean;
        float2 mz; mz.x = mean; mz.y = rsqrtf(var + 1e-5f);
        *(float2*)(musig + t * 2) = mz;
    }
    __syncthreads();

    #pragma unroll
    for (int mi = 0; mi < 2; ++mi)
        #pragma unroll
        for (int r = 0; r < 16; ++r) {
            int row = wm * 64 + mi * 32 + (r & 3) + 8 * (r >> 2) + 4 * lh;
            float2 mz = *(const float2*)(musig + row * 2);
            #pragma unroll
            for (int nf = 0; nf < 4; ++nf) {
                float xn = (acc[mi][nf][r] - mz.x) * mz.y * lnw_v[nf] + lnb_v[nf];
                out[(rb + row) * HH + wn * 128 + nf * 32 + l31] = 1.0f / (1.0f + __expf(-xn));
            }
        }
#undef STAGE
}

extern "C" void kernel_launch(void* const* d_in, const int* in_sizes, int n_in,
                              void* d_out, int out_size, void* d_ws, size_t ws_size,
                              hipStream_t stream) {
    const float* X = (const float*)d_in[0];
    const float* A = (const float*)d_in[1];
    const float* W = (const float*)d_in[2];
    const float* bias = (const float*)d_in[3];
    const float* lnw = (const float*)d_in[4];
    const float* lnb = (const float*)d_in[5];
    float* out = (float*)d_out;

    u16* Xagg = (u16*)d_ws;                                  // B*N*D bf16 = 32 MB
    u16* Wb = (u16*)d_ws + (size_t)BB * NN * DD;             // H*D bf16 = 512 KB

    hipLaunchKernelGGL(wconv_kernel, dim3(256), dim3(256), 0, stream, W, Wb);
    hipLaunchKernelGGL(agg_kernel, dim3(512), dim3(256), 0, stream, X, A, Xagg);
    hipLaunchKernelGGL(gemm_ln_kernel, dim3(256), dim3(512), 0, stream, Xagg, Wb, bias, lnw, lnb, out);
}

// Round 5
// 89.558 us; speedup vs baseline: 1.0736x; 1.0578x over previous
//
#include <hip/hip_runtime.h>
#include <cstdint>

#define BB 256
#define NN 128
#define DD 512
#define HH 512

typedef __attribute__((ext_vector_type(8))) short bf16x8;
typedef __attribute__((ext_vector_type(16))) float f32x16;
typedef unsigned short u16;

static __device__ __forceinline__ u16 f2bf(float f) {
    union { float f; uint32_t u; } v; v.f = f;
    uint32_t u = v.u;
    return (u16)((u + 0x7FFFu + ((u >> 16) & 1u)) >> 16);
}

static __device__ __forceinline__ void gload16(const u16* g, u16* l) {
    __builtin_amdgcn_global_load_lds((const __attribute__((address_space(1))) void*)g,
                                     (__attribute__((address_space(3))) void*)l, 16, 0, 0);
}

// ---------------- W fp32 -> bf16 (once) ----------------
__global__ __launch_bounds__(256) void wconv_kernel(const float* __restrict__ W, u16* __restrict__ Wb) {
    int idx = (blockIdx.x * 256 + threadIdx.x) * 4;
    float4 v = *(const float4*)(W + idx);
    ushort4 o;
    o.x = f2bf(v.x); o.y = f2bf(v.y); o.z = f2bf(v.z); o.w = f2bf(v.w);
    *(ushort4*)(Wb + idx) = o;
}

// ---------------- Yt[b][h][m] = sum_d W[h][d] * X[b][m][d] ----------------
// grid 512: block = (batch, m-half of 64). 512 thr = 8 waves: hg=w>>1 (128 h-strip), mg=w&1 (32 m-strip)
__global__ __launch_bounds__(512, 2) void yt_gemm_kernel(const float* __restrict__ X, const u16* __restrict__ Wb,
                                                         u16* __restrict__ Yt) {
    __shared__ __align__(16) char smem[131072];   // Xb [64][512] bf16 swz (64K) | Wslab 2x[512][32] (2x32K)

    const int t = threadIdx.x;
    const int lane = t & 63;
    const int w = t >> 6;
    const int hg = w >> 1, mg = w & 1;
    const int l31 = lane & 31, lh = lane >> 5;
    const int batch = blockIdx.x >> 1, mh = blockIdx.x & 1;

    // stage X half (64 rows x 512 d) fp32 -> bf16, chunk-swizzled: chunk' = chunk ^ (row&7)
    const float* Xg = X + ((size_t)batch * NN + mh * 64) * DD;
    #pragma unroll
    for (int it = 0; it < 16; ++it) {
        int q = it * 512 + t;
        int r = q >> 7, c4 = q & 127;          // c4: float4 index within row (128 per row)
        float4 v = *(const float4*)(Xg + (size_t)r * DD + c4 * 4);
        ushort4 o;
        o.x = f2bf(v.x); o.y = f2bf(v.y); o.z = f2bf(v.z); o.w = f2bf(v.w);
        *(ushort4*)(smem + r * 1024 + (((c4 >> 1) ^ (r & 7)) << 4) + ((c4 & 1) << 3)) = o;
    }

#define STAGEW(KS, BUF)                                                                   \
    {                                                                                     \
        u16* dst_ = (u16*)(smem + 65536 + (BUF) * 32768);                                 \
        _Pragma("unroll")                                                                 \
        for (int it_ = 0; it_ < 4; ++it_) {                                               \
            int q_ = it_ * 512 + t;                                                       \
            int h_ = q_ >> 2, c_ = q_ & 3;                                                \
            gload16(Wb + (size_t)h_ * DD + (KS) * 32 + ((c_ ^ ((h_ >> 1) & 3)) * 8),      \
                    dst_ + q_ * 8);                                                       \
        }                                                                                 \
    }

    STAGEW(0, 0);

    f32x16 acc[4];
    #pragma unroll
    for (int hf = 0; hf < 4; ++hf)
        #pragma unroll
        for (int r = 0; r < 16; ++r)
            acc[hf][r] = 0.f;

    __syncthreads();   // drains X-stage ds_writes + W0 gloads

    for (int ks = 0; ks < 16; ++ks) {
        const int buf = ks & 1;
        if (ks < 15) {
            STAGEW(ks + 1, buf ^ 1);
            asm volatile("s_waitcnt vmcnt(4)" ::: "memory");
        } else {
            asm volatile("s_waitcnt vmcnt(0)" ::: "memory");
        }
        __builtin_amdgcn_s_barrier();
        asm volatile("" ::: "memory");

        const u16* wl = (const u16*)(smem + 65536 + buf * 32768);
        const u16* xb = (const u16*)smem;
        #pragma unroll
        for (int s = 0; s < 2; ++s) {
            const int kc = s * 2 + lh;          // 16B chunk within BK=32
            bf16x8 af[4];
            #pragma unroll
            for (int hf = 0; hf < 4; ++hf) {
                int h = hg * 128 + hf * 32 + l31;
                af[hf] = *(const bf16x8*)(wl + h * 32 + ((kc ^ ((h >> 1) & 3)) * 8));
            }
            int m = mg * 32 + l31;
            int gc = ks * 4 + kc;               // global 16B chunk 0..63
            bf16x8 bw = *(const bf16x8*)(xb + m * 512 + ((gc ^ (m & 7)) * 8));
            #pragma unroll
            for (int hf = 0; hf < 4; ++hf)
                acc[hf] = __builtin_amdgcn_mfma_f32_32x32x16_bf16(af[hf], bw, acc[hf], 0, 0, 0);
        }
        asm volatile("" ::: "memory");
        __builtin_amdgcn_s_barrier();
    }

    // write Yt: lane holds col m = mg*32+l31, rows h
    u16* Yg = Yt + (size_t)batch * (HH * NN) + mh * 64 + mg * 32 + l31;
    #pragma unroll
    for (int hf = 0; hf < 4; ++hf)
        #pragma unroll
        for (int r = 0; r < 16; ++r) {
            int h = hg * 128 + hf * 32 + (r & 3) + 8 * (r >> 2) + 4 * lh;
            Yg[(size_t)h * NN] = f2bf(acc[hf][r]);
        }
#undef STAGEW
}

// ---------------- out = sigmoid(LN( (I + A_norm) @ Y + bias )) ----------------
// grid 512: (batch, i-half of 64); 512 thr; wave w -> h in [w*64, w*64+64)
__global__ __launch_bounds__(512, 2) void aggln_kernel(const float* __restrict__ A, const u16* __restrict__ Yt,
                                                       const float* __restrict__ bias, const float* __restrict__ lnw,
                                                       const float* __restrict__ lnb, float* __restrict__ out) {
    __shared__ __align__(16) char smem[147456];  // Yl [512][128] bf16 (128K) | Ml [64][128] bf16 (16K)
    u16* Yl = (u16*)smem;
    u16* Ml = (u16*)(smem + 131072);
    float* Pss = (float*)(smem + 131072);        // overlay after compute: [512] float2
    float* musig = (float*)(smem + 131072 + 4096);  // [64] float2

    const int t = threadIdx.x;
    const int lane = t & 63, w = t >> 6, l31 = lane & 31, lh = lane >> 5;
    const int bid = ((int)blockIdx.x & 7) * 64 + ((int)blockIdx.x >> 3);   // XCD-chunked: batch pairs co-XCD
    const int batch = bid >> 1, ih = bid & 1;

    // A row loads (issue first)
    const int arow = t >> 3, seg = t & 7;
    const float* Ag = A + ((size_t)batch * NN + ih * 64 + arow) * NN + seg * 16;
    float4 av0 = *(const float4*)(Ag);
    float4 av1 = *(const float4*)(Ag + 4);
    float4 av2 = *(const float4*)(Ag + 8);
    float4 av3 = *(const float4*)(Ag + 12);

    float bias_v[2], lnw_v[2], lnb_v[2];
    #pragma unroll
    for (int fh = 0; fh < 2; ++fh) {
        int h = w * 64 + fh * 32 + l31;
        bias_v[fh] = bias[h];
        lnw_v[fh] = lnw[h];
        lnb_v[fh] = lnb[h];
    }

    // stage Yt[b] (full 512x128 bf16), source chunk-swizzled: chunk' = chunk ^ (h&7)
    const u16* Yg = Yt + (size_t)batch * (HH * NN);
    #pragma unroll
    for (int it = 0; it < 16; ++it) {
        int q = it * 512 + t;
        int h = q >> 4, c = q & 15;
        gload16(Yg + h * NN + ((c ^ (h & 7)) * 8), Yl + q * 8);
    }

    // build M = A_norm + I (bf16, swizzled)
    {
        float s = av0.x + av0.y + av0.z + av0.w + av1.x + av1.y + av1.z + av1.w
                + av2.x + av2.y + av2.z + av2.w + av3.x + av3.y + av3.z + av3.w;
        s += __shfl_xor(s, 1);
        s += __shfl_xor(s, 2);
        s += __shfl_xor(s, 4);
        float inv = 1.0f / (s + 1e-6f);
        int ig = ih * 64 + arow;
        float fv[16] = {av0.x, av0.y, av0.z, av0.w, av1.x, av1.y, av1.z, av1.w,
                        av2.x, av2.y, av2.z, av2.w, av3.x, av3.y, av3.z, av3.w};
        ushort tmp[16];
        #pragma unroll
        for (int e = 0; e < 16; ++e) {
            int m = seg * 16 + e;
            float val = fv[e] * inv + (m == ig ? 1.0f : 0.0f);
            tmp[e] = f2bf(val);
        }
        *(uint4*)(Ml + arow * 128 + (((seg * 2) ^ (arow & 7)) * 8)) = *(const uint4*)&tmp[0];
        *(uint4*)(Ml + arow * 128 + (((seg * 2 + 1) ^ (arow & 7)) * 8)) = *(const uint4*)&tmp[8];
    }
    __syncthreads();   // M visible; own Yt gloads drained

    // compute: P[i][h] = sum_m M[i][m] * Yl[h][m]
    f32x16 acc[2][2];
    #pragma unroll
    for (int fi = 0; fi < 2; ++fi)
        #pragma unroll
        for (int fh = 0; fh < 2; ++fh)
            #pragma unroll
            for (int r = 0; r < 16; ++r)
                acc[fi][fh][r] = 0.f;

    #pragma unroll
    for (int s8 = 0; s8 < 8; ++s8) {
        const int kc = s8 * 2 + lh;    // m-chunk 0..15
        bf16x8 af[2], bw[2];
        #pragma unroll
        for (int fi = 0; fi < 2; ++fi) {
            int i = fi * 32 + l31;
            af[fi] = *(const bf16x8*)(Ml + i * 128 + ((kc ^ (i & 7)) * 8));
        }
        #pragma unroll
        for (int fh = 0; fh < 2; ++fh) {
            int h = w * 64 + fh * 32 + l31;
            bw[fh] = *(const bf16x8*)(Yl + h * 128 + ((kc ^ (h & 7)) * 8));
        }
        #pragma unroll
        for (int fi = 0; fi < 2; ++fi)
            #pragma unroll
            for (int fh = 0; fh < 2; ++fh)
                acc[fi][fh] = __builtin_amdgcn_mfma_f32_32x32x16_bf16(af[fi], bw[fh], acc[fi][fh], 0, 0, 0);
    }
    __syncthreads();   // M-reads done; overlay stats onto Ml region

    // bias + per-row stats (row sums over this wave's 64 h)
    float rs[2][16], rss[2][16];
    #pragma unroll
    for (int fi = 0; fi < 2; ++fi)
        #pragma unroll
        for (int r = 0; r < 16; ++r) {
            float a0 = acc[fi][0][r] + bias_v[0];
            float a1 = acc[fi][1][r] + bias_v[1];
            acc[fi][0][r] = a0; acc[fi][1][r] = a1;
            rs[fi][r] = a0 + a1;
            rss[fi][r] = a0 * a0 + a1 * a1;
        }
    #pragma unroll
    for (int msk = 1; msk <= 16; msk <<= 1) {
        #pragma unroll
        for (int fi = 0; fi < 2; ++fi)
            #pragma unroll
            for (int r = 0; r < 16; ++r) {
                rs[fi][r] += __shfl_xor(rs[fi][r], msk);
                rss[fi][r] += __shfl_xor(rss[fi][r], msk);
            }
    }
    if (l31 == 0) {
        #pragma unroll
        for (int fi = 0; fi < 2; ++fi)
            #pragma unroll
            for (int r = 0; r < 16; ++r) {
                int row = fi * 32 + (r & 3) + 8 * (r >> 2) + 4 * lh;
                float2 v; v.x = rs[fi][r]; v.y = rss[fi][r];
                *(float2*)(Pss + (w * 64 + row) * 2) = v;
            }
    }
    __syncthreads();
    if (t < 64) {
        float s = 0.f, ss = 0.f;
        #pragma unroll
        for (int q = 0; q < 8; ++q) {
            float2 v = *(const float2*)(Pss + (q * 64 + t) * 2);
            s += v.x; ss += v.y;
        }
        float mean = s * (1.0f / 512.0f);
        float var = ss * (1.0f / 512.0f) - mean * mean;
        float2 mz; mz.x = mean; mz.y = rsqrtf(var + 1e-5f);
        *(float2*)(musig + t * 2) = mz;
    }
    __syncthreads();

    // LN + sigmoid + store
    #pragma unroll
    for (int fi = 0; fi < 2; ++fi)
        #pragma unroll
        for (int r = 0; r < 16; ++r) {
            int row = fi * 32 + (r & 3) + 8 * (r >> 2) + 4 * lh;
            float2 mz = *(const float2*)(musig + row * 2);
            #pragma unroll
            for (int fh = 0; fh < 2; ++fh) {
                float xn = (acc[fi][fh][r] - mz.x) * mz.y * lnw_v[fh] + lnb_v[fh];
                out[((size_t)batch * NN + ih * 64 + row) * HH + w * 64 + fh * 32 + l31] =
                    1.0f / (1.0f + __expf(-xn));
            }
        }
}

extern "C" void kernel_launch(void* const* d_in, const int* in_sizes, int n_in,
                              void* d_out, int out_size, void* d_ws, size_t ws_size,
                              hipStream_t stream) {
    const float* X = (const float*)d_in[0];
    const float* A = (const float*)d_in[1];
    const float* W = (const float*)d_in[2];
    const float* bias = (const float*)d_in[3];
    const float* lnw = (const float*)d_in[4];
    const float* lnb = (const float*)d_in[5];
    float* out = (float*)d_out;

    u16* Yt = (u16*)d_ws;                                  // B*H*N bf16 = 32 MB
    u16* Wb = (u16*)d_ws + (size_t)BB * HH * NN;           // H*D bf16 = 512 KB

    hipLaunchKernelGGL(wconv_kernel, dim3(256), dim3(256), 0, stream, W, Wb);
    hipLaunchKernelGGL(yt_gemm_kernel, dim3(512), dim3(512), 0, stream, X, Wb, Yt);
    hipLaunchKernelGGL(aggln_kernel, dim3(512), dim3(512), 0, stream, A, Yt, bias, lnw, lnb, out);
}